// Round 5
// baseline (23.538 us; speedup 1.0000x reference)
//
#include <hip/hip_runtime.h>

#define NPOS 1024
#define NBATCH 64
#define DROW 2050
#define JCH 8        // j-chunks of 128 per batch
#define NBLK (NBATCH * 2 * JCH)   // (i-half, j-chunk) per batch = 16 blocks

// Fused kernel. Per block: rebuild the batch's 1024 pre-scaled positions in LDS
// (shuffle block-scan; P.w = -|p|^2), then thread t holds R=4 register
// positions pi[r] = P[ih*512 + (t&127) + 128r] and sweeps a 64-length j-range
// (j wave-uniform -> broadcast ds_read_b128, reused for 4*64 pairs).
// Full-matrix formulation, no masks: pair term = exp2(2 pi.q + pi.w + q.w)
// = exp2(-|pi-q|^2); the i==j diagonal contributes exactly 1.0 (bit-identical
// FMA order between scan's |p|^2 and the pair dot product) and is subtracted
// as a constant in the reduce kernel. Positions pre-scaled by
// ALPHA = sqrt(4*log2 e) so exp(-4 d2) == exp2(-|dp|^2).
__global__ __launch_bounds__(256) void fused_kernel(const float* __restrict__ conf,
                                                    float* __restrict__ part) {
  __shared__ float4 P[NPOS];   // 16 KB
  __shared__ float wx[4], wy[4], wz[4];
  __shared__ float red[4];

  const int g = blockIdx.x % (2 * JCH);   // 0..15: (i-half, j-chunk)
  const int b = blockIdx.x / (2 * JCH);
  const int ih = g >> 3;                  // i half: 0 or 1
  const int jc = g & 7;                   // j chunk
  const int tid = threadIdx.x;
  const int lane = tid & 63, w = tid >> 6;
  const float* __restrict__ row = conf + b * DROW;
  const float ALPHA = 2.40224481f;  // sqrt(4*log2(e)) = sqrt(5.770780163555856)

  // ---- phase 1: chain scan -> LDS positions ----
  float lx[4], ly[4], lz[4];
  float rx = 0.f, ry = 0.f, rz = 0.f;
#pragma unroll
  for (int k = 0; k < 4; ++k) {
    const int n = 4 * tid + k;
    if (n > 0) {
      const float2 rr = *reinterpret_cast<const float2*>(row + 2 + 2 * n);
      const float r1 = rr.x + 0.5f;
      const float r2 = rr.y + 0.5f;
      const float ct = 1.f - 2.f * r2;                    // cos(theta)
      const float st = sqrtf(fmaxf(0.f, 1.f - ct * ct));  // sin(theta)
      const float sp = __builtin_amdgcn_sinf(r1);         // sin(2*pi*r1)
      const float cp = __builtin_amdgcn_cosf(r1);
      rx += st * cp; ry += st * sp; rz += ct;
    }
    lx[k] = rx; ly[k] = ry; lz[k] = rz;
  }
  const float tx = rx, ty = ry, tz = rz;
  float sx = rx, sy = ry, sz = rz;
#pragma unroll
  for (int off = 1; off < 64; off <<= 1) {
    const float ax = __shfl_up(sx, off, 64);
    const float ay = __shfl_up(sy, off, 64);
    const float az = __shfl_up(sz, off, 64);
    if (lane >= off) { sx += ax; sy += ay; sz += az; }
  }
  if (lane == 63) { wx[w] = sx; wy[w] = sy; wz[w] = sz; }
  __syncthreads();
  float cx = 0.f, cy = 0.f, cz = 0.f;
#pragma unroll
  for (int ww = 0; ww < 3; ++ww)
    if (ww < w) { cx += wx[ww]; cy += wy[ww]; cz += wz[ww]; }

  const float ox = row[1] + cx + (sx - tx);  // init + exclusive prefix
  const float oy = row[2] + cy + (sy - ty);
  const float oz = row[3] + cz + (sz - tz);
#pragma unroll
  for (int k = 0; k < 4; ++k) {
    const float X = ALPHA * (ox + lx[k]);
    const float Y = ALPHA * (oy + ly[k]);
    const float Z = ALPHA * (oz + lz[k]);
    float n2 = X * X; n2 = fmaf(Y, Y, n2); n2 = fmaf(Z, Z, n2);  // same op order as pair dot
    P[4 * tid + k] = make_float4(X, Y, Z, -n2);
  }
  __syncthreads();

  // ---- phase 2: R=4 register i-tile vs 64 broadcast j's ----
  const int tl = tid & 127;
  const int half = tid >> 7;  // wave-uniform: waves 0-1 -> 0, waves 2-3 -> 1
  const float4 pi0 = P[ih * 512 + tl];
  const float4 pi1 = P[ih * 512 + tl + 128];
  const float4 pi2 = P[ih * 512 + tl + 256];
  const float4 pi3 = P[ih * 512 + tl + 384];
  const float4* __restrict__ PJ = &P[jc * 128 + half * 64];

  float a0 = 0.f, a1 = 0.f, a2 = 0.f, a3 = 0.f;
#pragma unroll 4
  for (int jj = 0; jj < 64; ++jj) {
    const float4 q = PJ[jj];   // wave-uniform address -> broadcast
    float t0 = pi0.x * q.x; t0 = fmaf(pi0.y, q.y, t0); t0 = fmaf(pi0.z, q.z, t0);
    float t1 = pi1.x * q.x; t1 = fmaf(pi1.y, q.y, t1); t1 = fmaf(pi1.z, q.z, t1);
    float t2 = pi2.x * q.x; t2 = fmaf(pi2.y, q.y, t2); t2 = fmaf(pi2.z, q.z, t2);
    float t3 = pi3.x * q.x; t3 = fmaf(pi3.y, q.y, t3); t3 = fmaf(pi3.z, q.z, t3);
    a0 += __builtin_amdgcn_exp2f(fmaf(2.f, t0, pi0.w + q.w));
    a1 += __builtin_amdgcn_exp2f(fmaf(2.f, t1, pi1.w + q.w));
    a2 += __builtin_amdgcn_exp2f(fmaf(2.f, t2, pi2.w + q.w));
    a3 += __builtin_amdgcn_exp2f(fmaf(2.f, t3, pi3.w + q.w));
  }

  // ---- block reduce -> one partial per block ----
  float acc = (a0 + a1) + (a2 + a3);
#pragma unroll
  for (int off = 32; off; off >>= 1) acc += __shfl_down(acc, off, 64);
  if (lane == 0) red[w] = acc;
  __syncthreads();
  if (tid == 0) part[blockIdx.x] = (red[0] + red[1]) + (red[2] + red[3]);
}

__global__ __launch_bounds__(256) void reduce_kernel(const float* __restrict__ part,
                                                     float* __restrict__ out) {
  float s = 0.f;
  for (int i = threadIdx.x; i < NBLK; i += 256) s += part[i];
#pragma unroll
  for (int off = 32; off; off >>= 1) s += __shfl_down(s, off, 64);
  __shared__ float red[4];
  const int lane = threadIdx.x & 63, w = threadIdx.x >> 6;
  if (lane == 0) red[w] = s;
  __syncthreads();
  if (threadIdx.x == 0) {
    // SIGMA * (full-matrix sum - exact diagonal contribution NPOS*NBATCH)
    out[0] = 10.0f * ((red[0] + red[1]) + (red[2] + red[3])) - 655360.0f;
  }
}

extern "C" void kernel_launch(void* const* d_in, const int* in_sizes, int n_in,
                              void* d_out, int out_size, void* d_ws, size_t ws_size,
                              hipStream_t stream) {
  const float* conf = (const float*)d_in[0];
  float* out = (float*)d_out;
  float* part = (float*)d_ws;  // NBLK floats
  hipLaunchKernelGGL(fused_kernel, dim3(NBLK), dim3(256), 0, stream, conf, part);
  hipLaunchKernelGGL(reduce_kernel, dim3(1), dim3(256), 0, stream, part, out);
}